// Round 1
// baseline (1766.479 us; speedup 1.0000x reference)
//
#include <hip/hip_runtime.h>

// InitReduceConv: out[dst[e], :] += x[src[e], :]  (E edges, D=64 fp32 features)
//
// d_in[0]: boundary_x     float32 [N_SRC * 64]
// d_in[1]: boundary_index int     [2 * E]   (row 0 = src idx, row 1 = dst idx)
// d_in[2]: out_size       int     [1]       (unused on device; out rows = out_size/64)
// d_out  : float32 [N_OUT * 64]

__global__ void scatter_add_f4_kernel(const float4* __restrict__ x4,
                                      const int* __restrict__ bidx,
                                      float* __restrict__ out,
                                      int E) {
    int idx = blockIdx.x * blockDim.x + threadIdx.x;
    int total = E * 16;               // 16 float4-chunks per edge (64 floats)
    if (idx >= total) return;
    int e = idx >> 4;                 // edge id
    int c = idx & 15;                 // chunk id within the row
    int src = bidx[e];                // source row
    int dst = bidx[E + e];            // destination row
    float4 v = x4[(size_t)src * 16 + c];
    float* o = out + (size_t)dst * 64 + (c << 2);
    atomicAdd(o + 0, v.x);
    atomicAdd(o + 1, v.y);
    atomicAdd(o + 2, v.z);
    atomicAdd(o + 3, v.w);
}

extern "C" void kernel_launch(void* const* d_in, const int* in_sizes, int n_in,
                              void* d_out, int out_size, void* d_ws, size_t ws_size,
                              hipStream_t stream) {
    const float* x = (const float*)d_in[0];
    const int* bidx = (const int*)d_in[1];
    float* out = (float*)d_out;

    const int E = in_sizes[1] / 2;    // 2,000,000

    // Harness poisons d_out with 0xAA before every launch — zero it.
    hipMemsetAsync(d_out, 0, (size_t)out_size * sizeof(float), stream);

    const int total = E * 16;
    const int block = 256;
    const int grid = (total + block - 1) / block;
    scatter_add_f4_kernel<<<grid, block, 0, stream>>>(
        (const float4*)x, bidx, out, E);
}

// Round 2
// 322.409 us; speedup vs baseline: 5.4790x; 5.4790x over previous
//
#include <hip/hip_runtime.h>

// InitReduceConv: out[dst[e], :] += x[src[e], :]  (E=2M edges, D=64 fp32)
//
// Strategy: scatter->gather conversion.
//  1. memset cursor/overflow region of ws
//  2. bucket_kernel:  pos = atomicAdd(cursor[dst]); bucket[dst][pos] = src
//     (capacity 64/row; overflow -> side list, statistically never for
//      Poisson(20) degrees, but handled for guaranteed correctness)
//  3. gather_sum_kernel: 16 lanes per output row, float4/lane, sum the
//     bucketed src rows, write out exactly once (no memset of out needed)
//  4. overflow_kernel: atomicAdd any overflow entries (count==0 in practice)
//
// ws layout: [0, 400K)   cursor  (N_OUT ints)
//            [512K, ~768K) ovf    (count + 32768 (src,dst) pairs)
//            [1M, 1M+25.6M) bucket (N_OUT * 64 ints)

#define CAP 64
#define OVF_CAP 32768
#define CURSOR_OFF 0
#define OVF_OFF (512u * 1024u)
#define BUCKET_OFF (1024u * 1024u)

__global__ void bucket_kernel(const int* __restrict__ bidx,
                              int* __restrict__ cursor,
                              int* __restrict__ bucket,
                              int* __restrict__ ovf,
                              int E) {
    int e = blockIdx.x * blockDim.x + threadIdx.x;
    if (e >= E) return;
    int src = bidx[e];
    int dst = bidx[E + e];
    int pos = atomicAdd(&cursor[dst], 1);
    if (pos < CAP) {
        bucket[dst * CAP + pos] = src;
    } else {
        int p = atomicAdd(&ovf[0], 1);
        if (p < OVF_CAP) {
            ovf[1 + 2 * p] = src;
            ovf[2 + 2 * p] = dst;
        }
    }
}

// 16 threads per output row, one float4 each.
__global__ void gather_sum_kernel(const float4* __restrict__ x4,
                                  const int* __restrict__ cursor,
                                  const int* __restrict__ bucket,
                                  float4* __restrict__ out4,
                                  int NOUT) {
    int t = blockIdx.x * blockDim.x + threadIdx.x;
    int row = t >> 4;
    int c = t & 15;
    if (row >= NOUT) return;
    int deg = cursor[row];
    if (deg > CAP) deg = CAP;
    const int* __restrict__ b = bucket + row * CAP;
    float4 acc = {0.f, 0.f, 0.f, 0.f};
    for (int j = 0; j < deg; ++j) {
        int src = b[j];
        float4 v = x4[(size_t)src * 16 + c];
        acc.x += v.x; acc.y += v.y; acc.z += v.z; acc.w += v.w;
    }
    out4[(size_t)row * 16 + c] = acc;
}

// Handles the (statistically nonexistent) overflow entries. block=64.
__global__ void overflow_kernel(const float* __restrict__ x,
                                const int* __restrict__ ovf,
                                float* __restrict__ out) {
    int n = ovf[0];
    if (n > OVF_CAP) n = OVF_CAP;
    for (int i = blockIdx.x; i < n; i += gridDim.x) {
        int src = ovf[1 + 2 * i];
        int dst = ovf[2 + 2 * i];
        atomicAdd(&out[(size_t)dst * 64 + threadIdx.x],
                  x[(size_t)src * 64 + threadIdx.x]);
    }
}

// Fallback (ws too small): round-1 direct atomic kernel.
__global__ void scatter_add_f4_kernel(const float4* __restrict__ x4,
                                      const int* __restrict__ bidx,
                                      float* __restrict__ out,
                                      int E) {
    int idx = blockIdx.x * blockDim.x + threadIdx.x;
    int total = E * 16;
    if (idx >= total) return;
    int e = idx >> 4;
    int c = idx & 15;
    int src = bidx[e];
    int dst = bidx[E + e];
    float4 v = x4[(size_t)src * 16 + c];
    float* o = out + (size_t)dst * 64 + (c << 2);
    atomicAdd(o + 0, v.x);
    atomicAdd(o + 1, v.y);
    atomicAdd(o + 2, v.z);
    atomicAdd(o + 3, v.w);
}

extern "C" void kernel_launch(void* const* d_in, const int* in_sizes, int n_in,
                              void* d_out, int out_size, void* d_ws, size_t ws_size,
                              hipStream_t stream) {
    const float* x = (const float*)d_in[0];
    const int* bidx = (const int*)d_in[1];
    float* out = (float*)d_out;

    const int E = in_sizes[1] / 2;     // 2,000,000
    const int NOUT = out_size / 64;    // 100,000

    size_t needed = (size_t)BUCKET_OFF + (size_t)NOUT * CAP * sizeof(int);
    if (ws_size < needed) {
        // Fallback: direct atomics (correct, slow).
        hipMemsetAsync(d_out, 0, (size_t)out_size * sizeof(float), stream);
        int total = E * 16;
        scatter_add_f4_kernel<<<(total + 255) / 256, 256, 0, stream>>>(
            (const float4*)x, bidx, out, E);
        return;
    }

    char* ws = (char*)d_ws;
    int* cursor = (int*)(ws + CURSOR_OFF);
    int* ovf = (int*)(ws + OVF_OFF);
    int* bucket = (int*)(ws + BUCKET_OFF);

    // Zero cursor + overflow count (both live in the first 1 MB).
    hipMemsetAsync(ws, 0, BUCKET_OFF, stream);

    bucket_kernel<<<(E + 255) / 256, 256, 0, stream>>>(bidx, cursor, bucket, ovf, E);

    int gthreads = NOUT * 16;
    gather_sum_kernel<<<(gthreads + 255) / 256, 256, 0, stream>>>(
        (const float4*)x, cursor, bucket, (float4*)out, NOUT);

    overflow_kernel<<<64, 64, 0, stream>>>(x, ovf, out);
}

// Round 3
// 321.653 us; speedup vs baseline: 5.4919x; 1.0024x over previous
//
#include <hip/hip_runtime.h>

// InitReduceConv: out[dst[e], :] += x[src[e], :]  (E=2M edges, D=64 fp32)
//
// Pipeline: memset(cursor) -> bucket (4 edges/thread, 4-way MLP)
//           -> gather-sum (16 lanes/row, deg-loop unrolled x4, 4-way MLP)
//           -> overflow fixup (statistically empty)
//
// ws layout: [0, 400000)        cursor (N_OUT ints)
//            [400000, 400004)   ovf count
//            [400004, ...)      ovf (src,dst) pairs
//            [1M, 1M+25.6M)     bucket (N_OUT * 64 ints)

#define CAP 64
#define OVF_CAP 32768
#define BUCKET_OFF (1024u * 1024u)

__global__ void bucket_kernel4(const int* __restrict__ bidx,
                               int* __restrict__ cursor,
                               int* __restrict__ bucket,
                               int* __restrict__ ovf,
                               int E) {
    int q = blockIdx.x * blockDim.x + threadIdx.x;
    int e0 = q << 2;
    if (e0 >= E) return;

    if (e0 + 3 < E) {
        int4 s = *(const int4*)(bidx + e0);
        int4 d = *(const int4*)(bidx + E + e0);
        int p0 = atomicAdd(&cursor[d.x], 1);
        int p1 = atomicAdd(&cursor[d.y], 1);
        int p2 = atomicAdd(&cursor[d.z], 1);
        int p3 = atomicAdd(&cursor[d.w], 1);
        if (p0 < CAP) bucket[d.x * CAP + p0] = s.x;
        else { int p = atomicAdd(&ovf[0], 1); if (p < OVF_CAP) { ovf[1+2*p] = s.x; ovf[2+2*p] = d.x; } }
        if (p1 < CAP) bucket[d.y * CAP + p1] = s.y;
        else { int p = atomicAdd(&ovf[0], 1); if (p < OVF_CAP) { ovf[1+2*p] = s.y; ovf[2+2*p] = d.y; } }
        if (p2 < CAP) bucket[d.z * CAP + p2] = s.z;
        else { int p = atomicAdd(&ovf[0], 1); if (p < OVF_CAP) { ovf[1+2*p] = s.z; ovf[2+2*p] = d.z; } }
        if (p3 < CAP) bucket[d.w * CAP + p3] = s.w;
        else { int p = atomicAdd(&ovf[0], 1); if (p < OVF_CAP) { ovf[1+2*p] = s.w; ovf[2+2*p] = d.w; } }
    } else {
        for (int e = e0; e < E; ++e) {
            int src = bidx[e];
            int dst = bidx[E + e];
            int pos = atomicAdd(&cursor[dst], 1);
            if (pos < CAP) bucket[dst * CAP + pos] = src;
            else { int p = atomicAdd(&ovf[0], 1); if (p < OVF_CAP) { ovf[1+2*p] = src; ovf[2+2*p] = dst; } }
        }
    }
}

// 16 threads per output row, one float4 each; degree loop unrolled x4.
__global__ void gather_sum_kernel(const float4* __restrict__ x4,
                                  const int* __restrict__ cursor,
                                  const int* __restrict__ bucket,
                                  float4* __restrict__ out4,
                                  int NOUT) {
    int t = blockIdx.x * blockDim.x + threadIdx.x;
    int row = t >> 4;
    int c = t & 15;
    if (row >= NOUT) return;
    int deg = cursor[row];
    if (deg > CAP) deg = CAP;
    const int* __restrict__ b = bucket + row * CAP;
    const int4* __restrict__ b4 = (const int4*)b;

    float4 acc0 = {0.f, 0.f, 0.f, 0.f};
    float4 acc1 = {0.f, 0.f, 0.f, 0.f};
    int nfull = deg >> 2;
    for (int j4 = 0; j4 < nfull; ++j4) {
        int4 s = b4[j4];                       // 4 bucket entries, one 16B load
        float4 v0 = x4[(size_t)s.x * 16 + c];  // 4 independent gathers in flight
        float4 v1 = x4[(size_t)s.y * 16 + c];
        float4 v2 = x4[(size_t)s.z * 16 + c];
        float4 v3 = x4[(size_t)s.w * 16 + c];
        acc0.x += v0.x + v1.x; acc0.y += v0.y + v1.y;
        acc0.z += v0.z + v1.z; acc0.w += v0.w + v1.w;
        acc1.x += v2.x + v3.x; acc1.y += v2.y + v3.y;
        acc1.z += v2.z + v3.z; acc1.w += v2.w + v3.w;
    }
    for (int j = nfull << 2; j < deg; ++j) {
        int src = b[j];
        float4 v = x4[(size_t)src * 16 + c];
        acc0.x += v.x; acc0.y += v.y; acc0.z += v.z; acc0.w += v.w;
    }
    float4 r;
    r.x = acc0.x + acc1.x; r.y = acc0.y + acc1.y;
    r.z = acc0.z + acc1.z; r.w = acc0.w + acc1.w;
    out4[(size_t)row * 16 + c] = r;
}

__global__ void overflow_kernel(const float* __restrict__ x,
                                const int* __restrict__ ovf,
                                float* __restrict__ out) {
    int n = ovf[0];
    if (n > OVF_CAP) n = OVF_CAP;
    for (int i = blockIdx.x; i < n; i += gridDim.x) {
        int src = ovf[1 + 2 * i];
        int dst = ovf[2 + 2 * i];
        atomicAdd(&out[(size_t)dst * 64 + threadIdx.x],
                  x[(size_t)src * 64 + threadIdx.x]);
    }
}

// Fallback (ws too small): direct atomic kernel.
__global__ void scatter_add_f4_kernel(const float4* __restrict__ x4,
                                      const int* __restrict__ bidx,
                                      float* __restrict__ out,
                                      int E) {
    int idx = blockIdx.x * blockDim.x + threadIdx.x;
    int total = E * 16;
    if (idx >= total) return;
    int e = idx >> 4;
    int c = idx & 15;
    int src = bidx[e];
    int dst = bidx[E + e];
    float4 v = x4[(size_t)src * 16 + c];
    float* o = out + (size_t)dst * 64 + (c << 2);
    atomicAdd(o + 0, v.x);
    atomicAdd(o + 1, v.y);
    atomicAdd(o + 2, v.z);
    atomicAdd(o + 3, v.w);
}

extern "C" void kernel_launch(void* const* d_in, const int* in_sizes, int n_in,
                              void* d_out, int out_size, void* d_ws, size_t ws_size,
                              hipStream_t stream) {
    const float* x = (const float*)d_in[0];
    const int* bidx = (const int*)d_in[1];
    float* out = (float*)d_out;

    const int E = in_sizes[1] / 2;     // 2,000,000
    const int NOUT = out_size / 64;    // 100,000

    size_t needed = (size_t)BUCKET_OFF + (size_t)NOUT * CAP * sizeof(int);
    if (ws_size < needed) {
        hipMemsetAsync(d_out, 0, (size_t)out_size * sizeof(float), stream);
        int total = E * 16;
        scatter_add_f4_kernel<<<(total + 255) / 256, 256, 0, stream>>>(
            (const float4*)x, bidx, out, E);
        return;
    }

    char* ws = (char*)d_ws;
    int* cursor = (int*)ws;
    int* ovf = (int*)(ws + (size_t)NOUT * sizeof(int));
    int* bucket = (int*)(ws + BUCKET_OFF);

    // Zero cursor + overflow count only.
    hipMemsetAsync(ws, 0, (size_t)NOUT * sizeof(int) + sizeof(int), stream);

    int nquads = (E + 3) / 4;
    bucket_kernel4<<<(nquads + 255) / 256, 256, 0, stream>>>(bidx, cursor, bucket, ovf, E);

    int gthreads = NOUT * 16;
    gather_sum_kernel<<<(gthreads + 255) / 256, 256, 0, stream>>>(
        (const float4*)x, cursor, bucket, (float4*)out, NOUT);

    overflow_kernel<<<64, 64, 0, stream>>>(x, ovf, out);
}

// Round 6
// 239.701 us; speedup vs baseline: 7.3695x; 1.3419x over previous
//
#include <hip/hip_runtime.h>

// InitReduceConv: out[dst[e], :] += x[src[e], :]  (E=2M edges, D=64 fp32)
//
// Pipeline: memset(cursor) -> XCD-partitioned bucket build -> XCD-partitioned
//           gather-sum -> overflow fixup (statistically empty).
//
// XCD partitioning: dst class = dst & 7. Each edge chunk is processed by 8
// blocks; block with (blockIdx&7)==p handles only dsts of class p. With the
// empirical round-robin block->XCD dispatch, all writes to a given bucket
// line then come from one XCD and combine in its private L2 before eviction
// (fixes the 120 MB scattered-write traffic of the unpartitioned version).
// Correctness does not depend on the dispatch mapping, only locality.
//
// ws layout: [0, NOUT*4)            cursor (N_OUT ints)
//            [NOUT*4, +4)           ovf count
//            [NOUT*4+8, ...)        ovf (src,dst) pairs
//            [1M, 1M+25.6M)         bucket (N_OUT * 64 ints)

#define CAP 64
#define OVF_CAP 32768
#define BUCKET_OFF (1024u * 1024u)
#define EDGES_PER_THREAD 8

__global__ void bucket_xcd_kernel(const int* __restrict__ bidx,
                                  int* __restrict__ cursor,
                                  int* __restrict__ bucket,
                                  int* __restrict__ ovf,
                                  int E) {
    const int part = blockIdx.x & 7;
    const int chunk = blockIdx.x >> 3;
    int e0 = (chunk * blockDim.x + threadIdx.x) * EDGES_PER_THREAD;
    if (e0 >= E) return;

    if (e0 + EDGES_PER_THREAD <= E) {
        int4 s0 = *(const int4*)(bidx + e0);
        int4 s1 = *(const int4*)(bidx + e0 + 4);
        int4 d0 = *(const int4*)(bidx + E + e0);
        int4 d1 = *(const int4*)(bidx + E + e0 + 4);
        int ss[8] = {s0.x, s0.y, s0.z, s0.w, s1.x, s1.y, s1.z, s1.w};
        int dd[8] = {d0.x, d0.y, d0.z, d0.w, d1.x, d1.y, d1.z, d1.w};
#pragma unroll
        for (int k = 0; k < 8; ++k) {
            int dst = dd[k];
            if ((dst & 7) != part) continue;
            int pos = atomicAdd(&cursor[dst], 1);
            if (pos < CAP) {
                bucket[dst * CAP + pos] = ss[k];
            } else {
                int p = atomicAdd(&ovf[0], 1);
                if (p < OVF_CAP) { ovf[1 + 2 * p] = ss[k]; ovf[2 + 2 * p] = dst; }
            }
        }
    } else {
        for (int e = e0; e < E; ++e) {
            int dst = bidx[E + e];
            if ((dst & 7) != part) continue;
            int src = bidx[e];
            int pos = atomicAdd(&cursor[dst], 1);
            if (pos < CAP) {
                bucket[dst * CAP + pos] = src;
            } else {
                int p = atomicAdd(&ovf[0], 1);
                if (p < OVF_CAP) { ovf[1 + 2 * p] = src; ovf[2 + 2 * p] = dst; }
            }
        }
    }
}

// 16 threads per output row, one float4 each; rows of class p handled by
// blocks with (blockIdx&7)==p so bucket lines are read on the XCD that
// wrote them. Degree loop unrolled x4 for MLP.
__global__ void gather_xcd_kernel(const float4* __restrict__ x4,
                                  const int* __restrict__ cursor,
                                  const int* __restrict__ bucket,
                                  float4* __restrict__ out4,
                                  int NOUT) {
    const int part = blockIdx.x & 7;
    const int i = blockIdx.x >> 3;
    int t = i * blockDim.x + threadIdx.x;
    int lrow = t >> 4;
    int c = t & 15;
    int row = part + (lrow << 3);
    if (row >= NOUT) return;

    int deg = cursor[row];
    if (deg > CAP) deg = CAP;
    const int* __restrict__ b = bucket + row * CAP;
    const int4* __restrict__ b4 = (const int4*)b;

    float4 acc0 = {0.f, 0.f, 0.f, 0.f};
    float4 acc1 = {0.f, 0.f, 0.f, 0.f};
    int nfull = deg >> 2;
    for (int j4 = 0; j4 < nfull; ++j4) {
        int4 s = b4[j4];
        float4 v0 = x4[(size_t)s.x * 16 + c];
        float4 v1 = x4[(size_t)s.y * 16 + c];
        float4 v2 = x4[(size_t)s.z * 16 + c];
        float4 v3 = x4[(size_t)s.w * 16 + c];
        acc0.x += v0.x + v1.x; acc0.y += v0.y + v1.y;
        acc0.z += v0.z + v1.z; acc0.w += v0.w + v1.w;
        acc1.x += v2.x + v3.x; acc1.y += v2.y + v3.y;
        acc1.z += v2.z + v3.z; acc1.w += v2.w + v3.w;
    }
    for (int j = nfull << 2; j < deg; ++j) {
        int src = b[j];
        float4 v = x4[(size_t)src * 16 + c];
        acc0.x += v.x; acc0.y += v.y; acc0.z += v.z; acc0.w += v.w;
    }
    float4 r;
    r.x = acc0.x + acc1.x; r.y = acc0.y + acc1.y;
    r.z = acc0.z + acc1.z; r.w = acc0.w + acc1.w;
    out4[(size_t)row * 16 + c] = r;
}

__global__ void overflow_kernel(const float* __restrict__ x,
                                const int* __restrict__ ovf,
                                float* __restrict__ out) {
    int n = ovf[0];
    if (n > OVF_CAP) n = OVF_CAP;
    for (int i = blockIdx.x; i < n; i += gridDim.x) {
        int src = ovf[1 + 2 * i];
        int dst = ovf[2 + 2 * i];
        atomicAdd(&out[(size_t)dst * 64 + threadIdx.x],
                  x[(size_t)src * 64 + threadIdx.x]);
    }
}

// Fallbacks for unexpected shapes.
__global__ void bucket_kernel1(const int* __restrict__ bidx,
                               int* __restrict__ cursor,
                               int* __restrict__ bucket,
                               int* __restrict__ ovf,
                               int E) {
    int e = blockIdx.x * blockDim.x + threadIdx.x;
    if (e >= E) return;
    int src = bidx[e];
    int dst = bidx[E + e];
    int pos = atomicAdd(&cursor[dst], 1);
    if (pos < CAP) bucket[dst * CAP + pos] = src;
    else { int p = atomicAdd(&ovf[0], 1); if (p < OVF_CAP) { ovf[1+2*p] = src; ovf[2+2*p] = dst; } }
}

__global__ void scatter_add_f4_kernel(const float4* __restrict__ x4,
                                      const int* __restrict__ bidx,
                                      float* __restrict__ out,
                                      int E) {
    int idx = blockIdx.x * blockDim.x + threadIdx.x;
    int total = E * 16;
    if (idx >= total) return;
    int e = idx >> 4;
    int c = idx & 15;
    int src = bidx[e];
    int dst = bidx[E + e];
    float4 v = x4[(size_t)src * 16 + c];
    float* o = out + (size_t)dst * 64 + (c << 2);
    atomicAdd(o + 0, v.x);
    atomicAdd(o + 1, v.y);
    atomicAdd(o + 2, v.z);
    atomicAdd(o + 3, v.w);
}

extern "C" void kernel_launch(void* const* d_in, const int* in_sizes, int n_in,
                              void* d_out, int out_size, void* d_ws, size_t ws_size,
                              hipStream_t stream) {
    const float* x = (const float*)d_in[0];
    const int* bidx = (const int*)d_in[1];
    float* out = (float*)d_out;

    const int E = in_sizes[1] / 2;     // 2,000,000
    const int NOUT = out_size / 64;    // 100,000

    size_t needed = (size_t)BUCKET_OFF + (size_t)NOUT * CAP * sizeof(int);
    if (ws_size < needed) {
        hipMemsetAsync(d_out, 0, (size_t)out_size * sizeof(float), stream);
        int total = E * 16;
        scatter_add_f4_kernel<<<(total + 255) / 256, 256, 0, stream>>>(
            (const float4*)x, bidx, out, E);
        return;
    }

    char* ws = (char*)d_ws;
    int* cursor = (int*)ws;
    int* ovf = (int*)(ws + (size_t)NOUT * sizeof(int));
    int* bucket = (int*)(ws + BUCKET_OFF);

    // Zero cursor + overflow count only.
    hipMemsetAsync(ws, 0, (size_t)NOUT * sizeof(int) + 2 * sizeof(int), stream);

    if ((E & 7) == 0 && (E & 3) == 0) {
        // 8 partition-blocks per chunk of 256*8 edges.
        int nchunks = (E / EDGES_PER_THREAD + 255) / 256;
        bucket_xcd_kernel<<<nchunks * 8, 256, 0, stream>>>(bidx, cursor, bucket, ovf, E);
    } else {
        bucket_kernel1<<<(E + 255) / 256, 256, 0, stream>>>(bidx, cursor, bucket, ovf, E);
    }

    // Gather: 12500 rows per partition (NOUT=100k), 16 rows per block.
    int rows_per_part = (NOUT + 7) / 8;
    int blocks_per_part = (rows_per_part * 16 + 255) / 256;
    gather_xcd_kernel<<<blocks_per_part * 8, 256, 0, stream>>>(
        (const float4*)x, cursor, bucket, (float4*)out, NOUT);

    overflow_kernel<<<64, 64, 0, stream>>>(x, ovf, out);
}